// Round 2
// baseline (1097.811 us; speedup 1.0000x reference)
//
#include <hip/hip_runtime.h>
#include <cstdint>
#include <cstddef>

typedef unsigned short u16;
typedef __attribute__((ext_vector_type(4))) float f32x4;
typedef __attribute__((ext_vector_type(4))) unsigned int u32x4;

// ---------- bf16 helpers (bit-level) ----------
__device__ __forceinline__ float b2f(u16 u) {
  union { unsigned int i; float f; } x; x.i = ((unsigned int)u) << 16; return x.f;
}
__device__ __forceinline__ u16 f2b(float f) {
  union { float f; unsigned int i; } x; x.f = f;
  unsigned int i = x.i;
  i += 0x7fffu + ((i >> 16) & 1u);   // RNE
  return (u16)(i >> 16);
}

// ---------- MFMA via inline asm ----------
__device__ __forceinline__ void mfma_bf16(f32x4& c, u32x4 a, u32x4 b) {
  asm("v_mfma_f32_16x16x32_bf16 %0, %1, %2, %0" : "+v"(c) : "v"(a), "v"(b));
}

// ---------- async global->LDS, 16B per lane ----------
__device__ __forceinline__ void async_ld16(const u16* g, u16* l) {
  typedef __attribute__((address_space(1))) const unsigned int GU;
  typedef __attribute__((address_space(3))) unsigned int LU;
  __builtin_amdgcn_global_load_lds((GU*)g, (LU*)l, 16, 0, 0);
}

// =======================================================================
// Weight transpose + cast: in[K][ldin] f32 (use N cols) -> out[N][K] bf16
// grid = (K/64)*(N/64), block = 256
// =======================================================================
__global__ __launch_bounds__(256)
void transpose_cast_kernel(const float* __restrict__ in, u16* __restrict__ out,
                           int K, int N, int ldin) {
  __shared__ float tile[64][65];
  const int nb = N >> 6;
  const int bk = blockIdx.x / nb, bn = blockIdx.x % nb;
  const int k0 = bk * 64, n0 = bn * 64;
  const int tid = threadIdx.x;
#pragma unroll
  for (int p = 0; p < 16; ++p) {
    int idx = p * 256 + tid;
    int r = idx >> 6, c = idx & 63;
    tile[r][c] = in[(size_t)(k0 + r) * ldin + n0 + c];
  }
  __syncthreads();
#pragma unroll
  for (int p = 0; p < 16; ++p) {
    int idx = p * 256 + tid;
    int r = idx >> 6, c = idx & 63;
    out[(size_t)(n0 + r) * K + k0 + c] = f2b(tile[c][r]);
  }
}

// =======================================================================
// RMSNorm over 2048 f32 -> bf16.  grid = 4096 rows, block = 256
// =======================================================================
__global__ __launch_bounds__(256)
void rmsnorm_cast_kernel(const float* __restrict__ x, const float* __restrict__ w,
                         u16* __restrict__ out) {
  const int row = blockIdx.x, tid = threadIdx.x;
  const float* xr = x + (size_t)row * 2048;
  float4 a = ((const float4*)xr)[tid * 2];
  float4 b = ((const float4*)xr)[tid * 2 + 1];
  float ss = a.x*a.x + a.y*a.y + a.z*a.z + a.w*a.w
           + b.x*b.x + b.y*b.y + b.z*b.z + b.w*b.w;
#pragma unroll
  for (int m = 32; m; m >>= 1) ss += __shfl_xor(ss, m);
  __shared__ float ps[4];
  if ((tid & 63) == 0) ps[tid >> 6] = ss;
  __syncthreads();
  const float sc = rsqrtf((ps[0] + ps[1] + ps[2] + ps[3]) * (1.0f / 2048.0f) + 1e-6f);
  const int base = tid * 8;
  const float vals[8] = {a.x, a.y, a.z, a.w, b.x, b.y, b.z, b.w};
  union { u16 h[8]; uint4 v4[2]; } o;
#pragma unroll
  for (int j = 0; j < 8; ++j) o.h[j] = f2b(vals[j] * sc * w[base + j]);
  *(uint4*)&out[(size_t)row * 2048 + base] = o.v4[0];
  *(uint4*)&out[(size_t)row * 2048 + base + 8] = o.v4[1];
}

// =======================================================================
// RMSNorm over 2048 bf16 -> bf16.  grid = 4096 rows, block = 256
// =======================================================================
__global__ __launch_bounds__(256)
void rmsnorm_bf16_kernel(const u16* __restrict__ x, const float* __restrict__ w,
                         u16* __restrict__ out) {
  const int row = blockIdx.x, tid = threadIdx.x;
  union { uint4 v4; u16 h[8]; } p;
  p.v4 = *(const uint4*)&x[(size_t)row * 2048 + tid * 8];
  float v[8];
  float ss = 0.f;
#pragma unroll
  for (int j = 0; j < 8; ++j) { v[j] = b2f(p.h[j]); ss += v[j] * v[j]; }
#pragma unroll
  for (int m = 32; m; m >>= 1) ss += __shfl_xor(ss, m);
  __shared__ float ps[4];
  if ((tid & 63) == 0) ps[tid >> 6] = ss;
  __syncthreads();
  const float sc = rsqrtf((ps[0] + ps[1] + ps[2] + ps[3]) * (1.0f / 2048.0f) + 1e-6f);
  union { u16 h[8]; uint4 v4; } o;
#pragma unroll
  for (int j = 0; j < 8; ++j) o.h[j] = f2b(v[j] * sc * w[tid * 8 + j]);
  *(uint4*)&out[(size_t)row * 2048 + tid * 8] = o.v4;
}

// =======================================================================
// RoPE tables: cos/sin [2048][128] f32.  grid = 1024, block = 256
// =======================================================================
__global__ __launch_bounds__(256)
void rope_table_kernel(float* __restrict__ ct, float* __restrict__ st) {
  const int idx = blockIdx.x * 256 + threadIdx.x;  // 2048*128
  const int t = idx >> 7, i = idx & 127;
  const float e = -(float)i * (0.0078125f * log2f(10000.0f));
  const float ang = (float)t * exp2f(e);
  ct[idx] = cosf(ang);
  st[idx] = sinf(ang);
}

// =======================================================================
// RoPE apply in-place on bf16 [4096][8*256], non-interleaved halves of 128.
// grid = 4096, block = 256
// =======================================================================
__global__ __launch_bounds__(256)
void rope_apply_kernel(u16* __restrict__ x, const float* __restrict__ ct,
                       const float* __restrict__ st, float scale) {
  const int gid = blockIdx.x * 256 + threadIdx.x;  // 4096*8*32
  const int r = gid >> 8;
  const int rem = gid & 255;
  const int h = rem >> 5;
  const int i4 = (rem & 31) * 4;
  const int t = r & 2047;
  const size_t o1 = (size_t)r * 2048 + h * 256 + i4;
  union { ushort4 v; u16 h4[4]; } p1, p2, q1, q2;
  p1.v = *(ushort4*)&x[o1];
  p2.v = *(ushort4*)&x[o1 + 128];
  const float4 c = *(const float4*)&ct[t * 128 + i4];
  const float4 s = *(const float4*)&st[t * 128 + i4];
  const float cc[4] = {c.x, c.y, c.z, c.w};
  const float sn[4] = {s.x, s.y, s.z, s.w};
#pragma unroll
  for (int j = 0; j < 4; ++j) {
    float x1 = b2f(p1.h4[j]), x2 = b2f(p2.h4[j]);
    q1.h4[j] = f2b((x1 * cc[j] - x2 * sn[j]) * scale);
    q2.h4[j] = f2b((x2 * cc[j] + x1 * sn[j]) * scale);
  }
  *(ushort4*)&x[o1] = q1.v;
  *(ushort4*)&x[o1 + 128] = q2.v;
}

// =======================================================================
// GEMM: C[M,N] = A[M,K](bf16) x Bt[N,K](bf16), fp32 accum.
// 128x128 tile, 4 waves, 16x16x32 MFMA, global_load_lds staging.
// EPI: 1 bf16 store
//      2 f32 store of acc + b2f(hsrc[idx])        (final residual add)
//      3 bf16 store of silu(acc) * b2f(hsrc[idx]) (fused SwiGLU; Cout==hsrc ok)
//      4 bf16 store of acc + fsrc[idx]            (attn-out + hidden residual)
// grid = (M/128)*(N/128), block = 256.
// =======================================================================
template <int EPI>
__global__ __launch_bounds__(256, 2)
void gemm_bt(const u16* __restrict__ A, const u16* __restrict__ Bt,
             void* Cout, const float* fsrc, const u16* hsrc, int N, int K) {
  __shared__ __align__(16) u16 As[128 * 32];
  __shared__ __align__(16) u16 Bs[128 * 32];
  const int tid = threadIdx.x;
  const int l = tid & 63, w = tid >> 6;
  const int lr = l & 15, hi = l >> 4;
  const int nbn = N >> 7;
  const int bm = blockIdx.x / nbn, bn = blockIdx.x % nbn;
  const int f0 = w * 512 + l * 8;
  const int r0 = f0 >> 5, c0 = f0 & 31;
  const u16* ga0 = A + (size_t)(bm * 128 + r0) * K + c0;
  const u16* ga1 = ga0 + (size_t)64 * K;
  const u16* gb0 = Bt + (size_t)(bn * 128 + r0) * K + c0;
  const u16* gb1 = gb0 + (size_t)64 * K;
  u16* la = As + w * 512;
  u16* lb = Bs + w * 512;
  f32x4 acc[4][4];
#pragma unroll
  for (int m = 0; m < 4; ++m)
#pragma unroll
    for (int n = 0; n < 4; ++n) acc[m][n] = (f32x4){0.f, 0.f, 0.f, 0.f};
  const int wr = (w >> 1) * 64, wc = (w & 1) * 64;
  for (int k0 = 0; k0 < K; k0 += 32) {
    async_ld16(ga0 + k0, la);
    async_ld16(ga1 + k0, la + 2048);
    async_ld16(gb0 + k0, lb);
    async_ld16(gb1 + k0, lb + 2048);
    __syncthreads();
    u32x4 af[4], bfr[4];
#pragma unroll
    for (int m = 0; m < 4; ++m)
      af[m] = *(const u32x4*)&As[(wr + m * 16 + lr) * 32 + hi * 8];
#pragma unroll
    for (int n = 0; n < 4; ++n)
      bfr[n] = *(const u32x4*)&Bs[(wc + n * 16 + lr) * 32 + hi * 8];
#pragma unroll
    for (int m = 0; m < 4; ++m)
#pragma unroll
      for (int n = 0; n < 4; ++n) mfma_bf16(acc[m][n], af[m], bfr[n]);
    __syncthreads();
  }
  const size_t crow0 = (size_t)(bm * 128 + wr);
  const int ccol0 = bn * 128 + wc;
#pragma unroll
  for (int m = 0; m < 4; ++m)
#pragma unroll
    for (int n = 0; n < 4; ++n)
#pragma unroll
      for (int j = 0; j < 4; ++j) {
        size_t r = crow0 + m * 16 + hi * 4 + j;
        size_t c = (size_t)(ccol0 + n * 16 + lr);
        size_t idx = r * N + c;
        float a = acc[m][n][j];
        if (EPI == 1) {
          ((u16*)Cout)[idx] = f2b(a);
        } else if (EPI == 2) {
          ((float*)Cout)[idx] = a + b2f(hsrc[idx]);
        } else if (EPI == 3) {
          float u = b2f(hsrc[idx]);
          ((u16*)Cout)[idx] = f2b(a / (1.0f + expf(-a)) * u);
        } else {
          ((u16*)Cout)[idx] = f2b(a + fsrc[idx]);
        }
      }
}

// =======================================================================
// Chunkwise retention scan.
// grid = 128 = (b:2)*(h:8)*(slice:8 of Dv=64), block = 256 (4 waves).
// State S^T[e(64)][d(256)] fp32 in MFMA accumulators (wave w: rows w*16..).
// q (pre-scaled+roped), k (roped), v: bf16; o: bf16 [4096][4096].
// LDS: 3*33.8 + 36.9 + 9.2 + 9.2 = 156.7 KB (< 160 KB).
// =======================================================================
#define LGQ 264
#define LGV 72
__global__ __launch_bounds__(256)
void retention_kernel(const u16* __restrict__ q, const u16* __restrict__ k,
                      const u16* __restrict__ v, u16* __restrict__ o) {
  __shared__ __align__(16) u16 qs[64 * LGQ];
  __shared__ __align__(16) u16 ks[64 * LGQ];
  __shared__ __align__(16) u16 stb[64 * LGQ];
  __shared__ __align__(16) u16 ktd[256 * LGV];
  __shared__ __align__(16) u16 vts[64 * LGV];
  __shared__ __align__(16) u16 ab[64 * LGV];

  const int tid = threadIdx.x;
  const int l = tid & 63, w = tid >> 6;
  const int lr = l & 15, hi = l >> 4;
  const int bid = blockIdx.x;
  const int sl = bid & 7;
  const int hh = (bid >> 3) & 7;
  const int b = bid >> 6;
  const float gamma = 1.0f - exp2f(-5.0f - (float)hh);
  const float lg = log2f(gamma);
  const float cdk = exp2f(64.0f * lg);
  const int e0 = sl * 64;
  const float kd = exp2f((float)(63 - (tid >> 2)) * lg);  // k_decay for c=tid>>2

  f32x4 st[16];
#pragma unroll
  for (int t = 0; t < 16; ++t) st[t] = (f32x4){0.f, 0.f, 0.f, 0.f};

  for (int n = 0; n < 32; ++n) {
    const int row0 = b * 2048 + n * 64;
    // --- stb <- round(S^T) ---
#pragma unroll
    for (int t = 0; t < 16; ++t)
#pragma unroll
      for (int j = 0; j < 4; ++j)
        stb[(w * 16 + hi * 4 + j) * LGQ + t * 16 + lr] = f2b(st[t][j]);
    // --- stage q,k [64][256] ---
#pragma unroll
    for (int p = 0; p < 8; ++p) {
      int idx = p * 256 + tid;
      int c = idx >> 5, s = (idx & 31) * 8;
      *(uint4*)&qs[c * LGQ + s] =
          *(const uint4*)&q[(size_t)(row0 + c) * 2048 + hh * 256 + s];
      *(uint4*)&ks[c * LGQ + s] =
          *(const uint4*)&k[(size_t)(row0 + c) * 2048 + hh * 256 + s];
    }
    // --- vts = v^T [e][c] ---
    {
      int e = tid & 63, cq = tid >> 6;
#pragma unroll
      for (int cc = 0; cc < 16; ++cc) {
        int c = cq * 16 + cc;
        vts[e * LGV + c] = v[(size_t)(row0 + c) * 4096 + hh * 512 + e0 + e];
      }
    }
    // --- ktd = (k * k_decay)^T [d][c] ---
    {
      int c = tid >> 2, dq = (tid & 3) * 64;
      const u16* krow = k + (size_t)(row0 + c) * 2048 + hh * 256 + dq;
#pragma unroll
      for (int d8 = 0; d8 < 8; ++d8) {
        union { uint4 v4; u16 h[8]; } pk;
        pk.v4 = *(const uint4*)(krow + d8 * 8);
#pragma unroll
        for (int j = 0; j < 8; ++j)
          ktd[(dq + d8 * 8 + j) * LGV + c] = f2b(b2f(pk.h[j]) * kd);
      }
    }
    __syncthreads();

    // --- attn = q~ k^T, mask, -> ab ---
    f32x4 att[4];
#pragma unroll
    for (int jf = 0; jf < 4; ++jf) att[jf] = (f32x4){0.f, 0.f, 0.f, 0.f};
#pragma unroll
    for (int kk = 0; kk < 8; ++kk) {
      u32x4 a = *(const u32x4*)&qs[(w * 16 + lr) * LGQ + kk * 32 + hi * 8];
#pragma unroll
      for (int jf = 0; jf < 4; ++jf) {
        u32x4 bb = *(const u32x4*)&ks[(jf * 16 + lr) * LGQ + kk * 32 + hi * 8];
        mfma_bf16(att[jf], a, bb);
      }
    }
#pragma unroll
    for (int jf = 0; jf < 4; ++jf)
#pragma unroll
      for (int j = 0; j < 4; ++j) {
        int i = w * 16 + hi * 4 + j;
        int jc = jf * 16 + lr;
        float mv = (i >= jc) ? exp2f((float)(i - jc) * lg) : 0.0f;
        ab[i * LGV + jc] = f2b(att[jf][j] * mv);
      }
    __syncthreads();   // ab visible (same-wave use, but be safe)

    // --- o_cross = q~ @ S (rows scaled by gamma^(i+1) after) ---
    f32x4 occ[4];
#pragma unroll
    for (int ef = 0; ef < 4; ++ef) occ[ef] = (f32x4){0.f, 0.f, 0.f, 0.f};
#pragma unroll
    for (int kk = 0; kk < 8; ++kk) {
      u32x4 a = *(const u32x4*)&qs[(w * 16 + lr) * LGQ + kk * 32 + hi * 8];
#pragma unroll
      for (int ef = 0; ef < 4; ++ef) {
        u32x4 bb = *(const u32x4*)&stb[(ef * 16 + lr) * LGQ + kk * 32 + hi * 8];
        mfma_bf16(occ[ef], a, bb);
      }
    }
#pragma unroll
    for (int ef = 0; ef < 4; ++ef)
#pragma unroll
      for (int j = 0; j < 4; ++j) {
        int i = w * 16 + hi * 4 + j;
        occ[ef][j] *= exp2f((float)(i + 1) * lg);
      }
    // --- o_intra: attn @ v accumulate ---
#pragma unroll
    for (int kk = 0; kk < 2; ++kk) {
      u32x4 a = *(const u32x4*)&ab[(w * 16 + lr) * LGV + kk * 32 + hi * 8];
#pragma unroll
      for (int ef = 0; ef < 4; ++ef) {
        u32x4 bb = *(const u32x4*)&vts[(ef * 16 + lr) * LGV + kk * 32 + hi * 8];
        mfma_bf16(occ[ef], a, bb);
      }
    }
    // --- store o chunk (bf16) ---
#pragma unroll
    for (int ef = 0; ef < 4; ++ef)
#pragma unroll
      for (int j = 0; j < 4; ++j) {
        int i = w * 16 + hi * 4 + j;
        o[(size_t)(row0 + i) * 4096 + hh * 512 + e0 + ef * 16 + lr] = f2b(occ[ef][j]);
      }
    // --- S^T = cdk*S^T + v^T @ k~ ---
#pragma unroll
    for (int t = 0; t < 16; ++t) {
      st[t][0] *= cdk; st[t][1] *= cdk; st[t][2] *= cdk; st[t][3] *= cdk;
    }
#pragma unroll
    for (int kk = 0; kk < 2; ++kk) {
      u32x4 a = *(const u32x4*)&vts[(w * 16 + lr) * LGV + kk * 32 + hi * 8];
#pragma unroll
      for (int t = 0; t < 16; ++t) {
        u32x4 bb = *(const u32x4*)&ktd[(t * 16 + lr) * LGV + kk * 32 + hi * 8];
        mfma_bf16(st[t], a, bb);
      }
    }
    __syncthreads();
  }
}

// =======================================================================
// Gated head-RMSNorm IN PLACE on o (bf16): o = rmsnorm512(o)*gnw*silu(g)
// grid = 4096*8, block = 64
// =======================================================================
__global__ __launch_bounds__(64)
void gating_kernel(u16* __restrict__ o, const u16* __restrict__ g,
                   const float* __restrict__ gnw) {
  const int blk = blockIdx.x;              // r*8 + h
  const size_t base = (size_t)blk * 512;
  const int l = threadIdx.x;
  union { uint4 v4; u16 h[8]; } ov, gv;
  ov.v4 = *(const uint4*)&o[base + l * 8];
  float x[8];
  float ss = 0.f;
#pragma unroll
  for (int j = 0; j < 8; ++j) { x[j] = b2f(ov.h[j]); ss += x[j] * x[j]; }
#pragma unroll
  for (int m = 32; m; m >>= 1) ss += __shfl_xor(ss, m);
  const float sc = rsqrtf(ss * (1.0f / 512.0f) + 1e-6f);
  gv.v4 = *(const uint4*)&g[base + l * 8];
  union { u16 h[8]; uint4 v4; } ou;
#pragma unroll
  for (int j = 0; j < 8; ++j) {
    float gvf = b2f(gv.h[j]);
    float sig = 1.0f / (1.0f + expf(-gvf));
    ou.h[j] = f2b(x[j] * sc * gnw[l * 8 + j] * gvf * sig);
  }
  *(uint4*)&o[base + l * 8] = ou.v4;
}

// =======================================================================
// Workspace map (193.0 MB total):
//   W     23,068,672  weight-transpose scratch (serial reuse)
//   ctab   1,048,576
//   stab   1,048,576
//   hb    16,777,216  attn-normed h (bf16); later reused as h2b
//   qb    16,777,216
//   kb    16,777,216
//   vb    33,554,432  -- vb+gb region later reused as ybU/act (46.1 MB)
//   gb    33,554,432
//   ob    33,554,432  retention out (bf16); gating in place
//   resb  16,777,216  residual (bf16)
// =======================================================================
extern "C" void kernel_launch(void* const* d_in, const int* in_sizes, int n_in,
                              void* d_out, int out_size, void* d_ws, size_t ws_size,
                              hipStream_t stream) {
  (void)in_sizes; (void)n_in; (void)out_size; (void)ws_size;
  const float* hidden      = (const float*)d_in[0];
  const float* attn_norm_w = (const float*)d_in[1];
  const float* q_w         = (const float*)d_in[2];
  const float* k_w         = (const float*)d_in[3];
  const float* v_w         = (const float*)d_in[4];
  const float* g_w         = (const float*)d_in[5];
  const float* o_w         = (const float*)d_in[6];
  const float* gnorm_w     = (const float*)d_in[7];
  const float* mlp_norm_w  = (const float*)d_in[8];
  const float* gate_w      = (const float*)d_in[9];
  const float* down_w      = (const float*)d_in[10];
  float* outp = (float*)d_out;

  char* ws = (char*)d_ws;
  size_t off = 0;
  auto alloc = [&](size_t bytes) -> char* {
    char* p = ws + off;
    off += (bytes + 255) & ~(size_t)255;
    return p;
  };
  u16*   W    = (u16*)alloc(23068672ULL);       // max transposed weight (23.1MB)
  float* ctab = (float*)alloc(1048576ULL);
  float* stab = (float*)alloc(1048576ULL);
  u16*   hb   = (u16*)alloc(16777216ULL);       // also h2b
  u16*   qb   = (u16*)alloc(16777216ULL);
  u16*   kb   = (u16*)alloc(16777216ULL);
  u16*   vb   = (u16*)alloc(33554432ULL);
  u16*   gb   = (u16*)alloc(33554432ULL);
  u16*   ob   = (u16*)alloc(33554432ULL);
  u16*   resb = (u16*)alloc(16777216ULL);
  u16*   ybU  = vb;   // [4096][5632] bf16 = 46.1MB over vb+gb (67.1MB), used
                      // only after vb/gb are dead (post-gating)

  rope_table_kernel<<<1024, 256, 0, stream>>>(ctab, stab);
  rmsnorm_cast_kernel<<<4096, 256, 0, stream>>>(hidden, attn_norm_w, hb);

  // Q projection
  transpose_cast_kernel<<<1024, 256, 0, stream>>>(q_w, W, 2048, 2048, 2048);
  gemm_bt<1><<<512, 256, 0, stream>>>(hb, W, (void*)qb, nullptr, nullptr, 2048, 2048);
  // K projection
  transpose_cast_kernel<<<1024, 256, 0, stream>>>(k_w, W, 2048, 2048, 2048);
  gemm_bt<1><<<512, 256, 0, stream>>>(hb, W, (void*)kb, nullptr, nullptr, 2048, 2048);
  // V projection
  transpose_cast_kernel<<<2048, 256, 0, stream>>>(v_w, W, 2048, 4096, 4096);
  gemm_bt<1><<<1024, 256, 0, stream>>>(hb, W, (void*)vb, nullptr, nullptr, 4096, 2048);
  // G projection
  transpose_cast_kernel<<<2048, 256, 0, stream>>>(g_w, W, 2048, 4096, 4096);
  gemm_bt<1><<<1024, 256, 0, stream>>>(hb, W, (void*)gb, nullptr, nullptr, 4096, 2048);

  // RoPE (+ q scale 1/16)
  rope_apply_kernel<<<4096, 256, 0, stream>>>(qb, ctab, stab, 0.0625f);
  rope_apply_kernel<<<4096, 256, 0, stream>>>(kb, ctab, stab, 1.0f);

  // Retention scan -> ob (bf16)
  retention_kernel<<<128, 256, 0, stream>>>(qb, kb, vb, ob);

  // Gated head RMSNorm in place on ob
  gating_kernel<<<32768, 64, 0, stream>>>(ob, gb, gnorm_w);

  // O projection + residual(hidden) -> resb (bf16)
  transpose_cast_kernel<<<2048, 256, 0, stream>>>(o_w, W, 4096, 2048, 2048);
  gemm_bt<4><<<512, 256, 0, stream>>>(ob, W, (void*)resb, hidden, nullptr, 2048, 4096);

  // MLP RMSNorm (h2b reuses hb)
  rmsnorm_bf16_kernel<<<4096, 256, 0, stream>>>(resb, mlp_norm_w, hb);

  // Up-half GEMM -> ybU
  transpose_cast_kernel<<<2816, 256, 0, stream>>>(gate_w + 5632, W, 2048, 5632, 11264);
  gemm_bt<1><<<1408, 256, 0, stream>>>(hb, W, (void*)ybU, nullptr, nullptr, 5632, 2048);
  // Gate-half GEMM with fused SwiGLU, in place over ybU
  transpose_cast_kernel<<<2816, 256, 0, stream>>>(gate_w, W, 2048, 5632, 11264);
  gemm_bt<3><<<1408, 256, 0, stream>>>(hb, W, (void*)ybU, nullptr, ybU, 5632, 2048);

  // Down projection + residual(resb) -> d_out (f32)
  transpose_cast_kernel<<<2816, 256, 0, stream>>>(down_w, W, 5632, 2048, 2048);
  gemm_bt<2><<<512, 256, 0, stream>>>(ybU, W, (void*)outp, nullptr, resb, 2048, 5632);
}

// Round 3
// 1040.116 us; speedup vs baseline: 1.0555x; 1.0555x over previous
//
#include <hip/hip_runtime.h>
#include <cstdint>
#include <cstddef>

typedef unsigned short u16;
typedef __attribute__((ext_vector_type(4))) float f32x4;
typedef __attribute__((ext_vector_type(4))) unsigned int u32x4;

// ---------- bf16 helpers (bit-level) ----------
__device__ __forceinline__ float b2f(u16 u) {
  union { unsigned int i; float f; } x; x.i = ((unsigned int)u) << 16; return x.f;
}
__device__ __forceinline__ u16 f2b(float f) {
  union { float f; unsigned int i; } x; x.f = f;
  unsigned int i = x.i;
  i += 0x7fffu + ((i >> 16) & 1u);   // RNE
  return (u16)(i >> 16);
}

// ---------- MFMA via inline asm ----------
__device__ __forceinline__ void mfma_bf16(f32x4& c, u32x4 a, u32x4 b) {
  asm("v_mfma_f32_16x16x32_bf16 %0, %1, %2, %0" : "+v"(c) : "v"(a), "v"(b));
}

// ---------- async global->LDS, 16B per lane ----------
__device__ __forceinline__ void async_ld16(const u16* g, u16* l) {
  typedef __attribute__((address_space(1))) const unsigned int GU;
  typedef __attribute__((address_space(3))) unsigned int LU;
  __builtin_amdgcn_global_load_lds((GU*)g, (LU*)l, 16, 0, 0);
}

// =======================================================================
// Weight transpose + cast: in[K][ldin] f32 (use N cols) -> out[N][K] bf16
// grid = (K/64)*(N/64), block = 256
// =======================================================================
__global__ __launch_bounds__(256)
void transpose_cast_kernel(const float* __restrict__ in, u16* __restrict__ out,
                           int K, int N, int ldin) {
  __shared__ float tile[64][65];
  const int nb = N >> 6;
  const int bk = blockIdx.x / nb, bn = blockIdx.x % nb;
  const int k0 = bk * 64, n0 = bn * 64;
  const int tid = threadIdx.x;
#pragma unroll
  for (int p = 0; p < 16; ++p) {
    int idx = p * 256 + tid;
    int r = idx >> 6, c = idx & 63;
    tile[r][c] = in[(size_t)(k0 + r) * ldin + n0 + c];
  }
  __syncthreads();
#pragma unroll
  for (int p = 0; p < 16; ++p) {
    int idx = p * 256 + tid;
    int r = idx >> 6, c = idx & 63;
    out[(size_t)(n0 + r) * K + k0 + c] = f2b(tile[c][r]);
  }
}

// =======================================================================
// k transpose: kb [b*2048 + t][h*256 + d] bf16 -> kt [(b*8+h)*256 + d][t]
// grid = 2048 = b(2)*h(8)*tt(32)*dd(4), block 256
// =======================================================================
__global__ __launch_bounds__(256)
void transpose_k_kernel(const u16* __restrict__ kb, u16* __restrict__ kt) {
  __shared__ u16 tile[64][72];
  const int bid = blockIdx.x;
  const int dd = bid & 3, tt = (bid >> 2) & 31;
  const int h = (bid >> 7) & 7, b = bid >> 10;
  const int t0 = tt * 64, d0 = dd * 64;
  const int tid = threadIdx.x;
#pragma unroll
  for (int p = 0; p < 2; ++p) {
    int idx = p * 256 + tid;
    int r = idx >> 3, cq = (idx & 7) * 8;   // r: t-row, cq: d-col
    *(uint4*)&tile[r][cq] =
        *(const uint4*)&kb[(size_t)(b * 2048 + t0 + r) * 2048 + h * 256 + d0 + cq];
  }
  __syncthreads();
#pragma unroll
  for (int p = 0; p < 2; ++p) {
    int idx = p * 256 + tid;
    int r = idx >> 3, cq = (idx & 7) * 8;   // r: d-row, cq: t-col
    union { u16 h8[8]; uint4 v4; } o;
#pragma unroll
    for (int j = 0; j < 8; ++j) o.h8[j] = tile[cq + j][r];
    *(uint4*)&kt[((size_t)(b * 8 + h) * 256 + d0 + r) * 2048 + t0 + cq] = o.v4;
  }
}

// =======================================================================
// RMSNorm over 2048 f32 -> bf16.  grid = 4096 rows, block = 256
// =======================================================================
__global__ __launch_bounds__(256)
void rmsnorm_cast_kernel(const float* __restrict__ x, const float* __restrict__ w,
                         u16* __restrict__ out) {
  const int row = blockIdx.x, tid = threadIdx.x;
  const float* xr = x + (size_t)row * 2048;
  float4 a = ((const float4*)xr)[tid * 2];
  float4 b = ((const float4*)xr)[tid * 2 + 1];
  float ss = a.x*a.x + a.y*a.y + a.z*a.z + a.w*a.w
           + b.x*b.x + b.y*b.y + b.z*b.z + b.w*b.w;
#pragma unroll
  for (int m = 32; m; m >>= 1) ss += __shfl_xor(ss, m);
  __shared__ float ps[4];
  if ((tid & 63) == 0) ps[tid >> 6] = ss;
  __syncthreads();
  const float sc = rsqrtf((ps[0] + ps[1] + ps[2] + ps[3]) * (1.0f / 2048.0f) + 1e-6f);
  const int base = tid * 8;
  const float vals[8] = {a.x, a.y, a.z, a.w, b.x, b.y, b.z, b.w};
  union { u16 h[8]; uint4 v4[2]; } o;
#pragma unroll
  for (int j = 0; j < 8; ++j) o.h[j] = f2b(vals[j] * sc * w[base + j]);
  *(uint4*)&out[(size_t)row * 2048 + base] = o.v4[0];
  *(uint4*)&out[(size_t)row * 2048 + base + 8] = o.v4[1];
}

// =======================================================================
// RMSNorm over 2048 bf16 -> bf16.  grid = 4096 rows, block = 256
// =======================================================================
__global__ __launch_bounds__(256)
void rmsnorm_bf16_kernel(const u16* __restrict__ x, const float* __restrict__ w,
                         u16* __restrict__ out) {
  const int row = blockIdx.x, tid = threadIdx.x;
  union { uint4 v4; u16 h[8]; } p;
  p.v4 = *(const uint4*)&x[(size_t)row * 2048 + tid * 8];
  float v[8];
  float ss = 0.f;
#pragma unroll
  for (int j = 0; j < 8; ++j) { v[j] = b2f(p.h[j]); ss += v[j] * v[j]; }
#pragma unroll
  for (int m = 32; m; m >>= 1) ss += __shfl_xor(ss, m);
  __shared__ float ps[4];
  if ((tid & 63) == 0) ps[tid >> 6] = ss;
  __syncthreads();
  const float sc = rsqrtf((ps[0] + ps[1] + ps[2] + ps[3]) * (1.0f / 2048.0f) + 1e-6f);
  union { u16 h[8]; uint4 v4; } o;
#pragma unroll
  for (int j = 0; j < 8; ++j) o.h[j] = f2b(v[j] * sc * w[tid * 8 + j]);
  *(uint4*)&out[(size_t)row * 2048 + tid * 8] = o.v4;
}

// =======================================================================
// RoPE tables: cos/sin [2048][128] f32.  grid = 1024, block = 256
// =======================================================================
__global__ __launch_bounds__(256)
void rope_table_kernel(float* __restrict__ ct, float* __restrict__ st) {
  const int idx = blockIdx.x * 256 + threadIdx.x;  // 2048*128
  const int t = idx >> 7, i = idx & 127;
  const float e = -(float)i * (0.0078125f * log2f(10000.0f));
  const float ang = (float)t * exp2f(e);
  ct[idx] = cosf(ang);
  st[idx] = sinf(ang);
}

// =======================================================================
// RoPE apply in-place on bf16 [4096][8*256], non-interleaved halves of 128.
// grid = 4096, block = 256
// =======================================================================
__global__ __launch_bounds__(256)
void rope_apply_kernel(u16* __restrict__ x, const float* __restrict__ ct,
                       const float* __restrict__ st, float scale) {
  const int gid = blockIdx.x * 256 + threadIdx.x;  // 4096*8*32
  const int r = gid >> 8;
  const int rem = gid & 255;
  const int h = rem >> 5;
  const int i4 = (rem & 31) * 4;
  const int t = r & 2047;
  const size_t o1 = (size_t)r * 2048 + h * 256 + i4;
  union { ushort4 v; u16 h4[4]; } p1, p2, q1, q2;
  p1.v = *(ushort4*)&x[o1];
  p2.v = *(ushort4*)&x[o1 + 128];
  const float4 c = *(const float4*)&ct[t * 128 + i4];
  const float4 s = *(const float4*)&st[t * 128 + i4];
  const float cc[4] = {c.x, c.y, c.z, c.w};
  const float sn[4] = {s.x, s.y, s.z, s.w};
#pragma unroll
  for (int j = 0; j < 4; ++j) {
    float x1 = b2f(p1.h4[j]), x2 = b2f(p2.h4[j]);
    q1.h4[j] = f2b((x1 * cc[j] - x2 * sn[j]) * scale);
    q2.h4[j] = f2b((x2 * cc[j] + x1 * sn[j]) * scale);
  }
  *(ushort4*)&x[o1] = q1.v;
  *(ushort4*)&x[o1 + 128] = q2.v;
}

// =======================================================================
// GEMM: C[M,N] = A[M,K](bf16) x Bt[N,K](bf16), fp32 accum.
// 128x128 tile, 4 waves, 16x16x32 MFMA, global_load_lds staging.
// EPI: 1 bf16; 2 f32 acc + b2f(hsrc); 3 bf16 silu(acc)*b2f(hsrc); 4 bf16 acc+fsrc
// =======================================================================
template <int EPI>
__global__ __launch_bounds__(256, 2)
void gemm_bt(const u16* __restrict__ A, const u16* __restrict__ Bt,
             void* Cout, const float* fsrc, const u16* hsrc, int N, int K) {
  __shared__ __align__(16) u16 As[128 * 32];
  __shared__ __align__(16) u16 Bs[128 * 32];
  const int tid = threadIdx.x;
  const int l = tid & 63, w = tid >> 6;
  const int lr = l & 15, hi = l >> 4;
  const int nbn = N >> 7;
  const int bm = blockIdx.x / nbn, bn = blockIdx.x % nbn;
  const int f0 = w * 512 + l * 8;
  const int r0 = f0 >> 5, c0 = f0 & 31;
  const u16* ga0 = A + (size_t)(bm * 128 + r0) * K + c0;
  const u16* ga1 = ga0 + (size_t)64 * K;
  const u16* gb0 = Bt + (size_t)(bn * 128 + r0) * K + c0;
  const u16* gb1 = gb0 + (size_t)64 * K;
  u16* la = As + w * 512;
  u16* lb = Bs + w * 512;
  f32x4 acc[4][4];
#pragma unroll
  for (int m = 0; m < 4; ++m)
#pragma unroll
    for (int n = 0; n < 4; ++n) acc[m][n] = (f32x4){0.f, 0.f, 0.f, 0.f};
  const int wr = (w >> 1) * 64, wc = (w & 1) * 64;
  for (int k0 = 0; k0 < K; k0 += 32) {
    async_ld16(ga0 + k0, la);
    async_ld16(ga1 + k0, la + 2048);
    async_ld16(gb0 + k0, lb);
    async_ld16(gb1 + k0, lb + 2048);
    __syncthreads();
    u32x4 af[4], bfr[4];
#pragma unroll
    for (int m = 0; m < 4; ++m)
      af[m] = *(const u32x4*)&As[(wr + m * 16 + lr) * 32 + hi * 8];
#pragma unroll
    for (int n = 0; n < 4; ++n)
      bfr[n] = *(const u32x4*)&Bs[(wc + n * 16 + lr) * 32 + hi * 8];
#pragma unroll
    for (int m = 0; m < 4; ++m)
#pragma unroll
      for (int n = 0; n < 4; ++n) mfma_bf16(acc[m][n], af[m], bfr[n]);
    __syncthreads();
  }
  const size_t crow0 = (size_t)(bm * 128 + wr);
  const int ccol0 = bn * 128 + wc;
#pragma unroll
  for (int m = 0; m < 4; ++m)
#pragma unroll
    for (int n = 0; n < 4; ++n)
#pragma unroll
      for (int j = 0; j < 4; ++j) {
        size_t r = crow0 + m * 16 + hi * 4 + j;
        size_t c = (size_t)(ccol0 + n * 16 + lr);
        size_t idx = r * N + c;
        float a = acc[m][n][j];
        if (EPI == 1) {
          ((u16*)Cout)[idx] = f2b(a);
        } else if (EPI == 2) {
          ((float*)Cout)[idx] = a + b2f(hsrc[idx]);
        } else if (EPI == 3) {
          float u = b2f(hsrc[idx]);
          ((u16*)Cout)[idx] = f2b(a / (1.0f + expf(-a)) * u);
        } else {
          ((u16*)Cout)[idx] = f2b(a + fsrc[idx]);
        }
      }
}

// =======================================================================
// Chunkwise retention scan, v2.
// grid = 256 = (b:2)*(h:8)*(slice:16 of Dv=32), block = 512 (8 waves).
// Wave w: i-row block wr=w>>1 (attn/o rows), e block eb=w&1 (state rows).
// State S^T[e(32)][d(256)] fp32: wave holds 4 frags (e rows eb*16+.., d
// blocks wr*4..wr*4+3).  q in regs; k chunk + S snapshot + (k*kd)^T + v^T
// in LDS (~102 KB -> 1 block/CU, 8 waves = 2/SIMD, 256 CUs).
// =======================================================================
#define LGK 264
#define LGC 72
__global__ __launch_bounds__(512)
void retention_kernel(const u16* __restrict__ q, const u16* __restrict__ k,
                      const u16* __restrict__ kt, const u16* __restrict__ v,
                      u16* __restrict__ o) {
  __shared__ __align__(16) u16 ks[64 * LGK];    // k chunk [c][d256]
  __shared__ __align__(16) u16 stb[32 * LGK];   // S^T snapshot [e32][d256]
  __shared__ __align__(16) u16 ktd[256 * LGC];  // (k*kd)^T [d][c64]
  __shared__ __align__(16) u16 vts[32 * LGC];   // v^T [e32][c64]
  __shared__ __align__(16) u16 ab[64 * LGC];    // masked attn [i][j64]
  __shared__ float kdt[64];

  const int tid = threadIdx.x;
  const int l = tid & 63, w = tid >> 6;
  const int lr = l & 15, hi = l >> 4;
  const int wr = w >> 1;
  const int eb = w & 1;
  const int bid = blockIdx.x;
  const int sl = bid & 15;
  const int hh = (bid >> 4) & 7;
  const int b = bid >> 7;
  const float gamma = 1.0f - exp2f(-5.0f - (float)hh);
  const float lg = log2f(gamma);
  const float cdk = exp2f(64.0f * lg);
  const int e0 = sl * 32;

  if (tid < 64) kdt[tid] = exp2f((float)(63 - tid) * lg);
  __syncthreads();

  f32x4 st[4];
#pragma unroll
  for (int t = 0; t < 4; ++t) st[t] = (f32x4){0.f, 0.f, 0.f, 0.f};

  for (int n = 0; n < 32; ++n) {
    const int row0 = b * 2048 + n * 64;
    const int t0 = n * 64;
    // --- stb <- round(S^T) ---
#pragma unroll
    for (int t = 0; t < 4; ++t)
#pragma unroll
      for (int j = 0; j < 4; ++j)
        stb[(eb * 16 + hi * 4 + j) * LGK + (wr * 4 + t) * 16 + lr] = f2b(st[t][j]);
    // --- q fragments to regs (wave's 16 i-rows) ---
    u32x4 qf[8];
#pragma unroll
    for (int kk = 0; kk < 8; ++kk)
      qf[kk] = *(const u32x4*)&q[(size_t)(row0 + wr * 16 + lr) * 2048 +
                                 hh * 256 + kk * 32 + hi * 8];
    // --- stage ks [c][d] ---
#pragma unroll
    for (int p = 0; p < 4; ++p) {
      int idx = p * 512 + tid;
      int c = idx >> 5, s = (idx & 31) * 8;
      *(uint4*)&ks[c * LGK + s] =
          *(const uint4*)&k[(size_t)(row0 + c) * 2048 + hh * 256 + s];
    }
    // --- stage ktd [d][c] = kt * kd (coalesced rows from kt) ---
#pragma unroll
    for (int p = 0; p < 4; ++p) {
      int idx = p * 512 + tid;
      int d = idx >> 3, cq = (idx & 7) * 8;
      union { uint4 v4; u16 h[8]; } pk;
      pk.v4 = *(const uint4*)&kt[((size_t)(b * 8 + hh) * 256 + d) * 2048 + t0 + cq];
      union { u16 h[8]; uint4 v4; } wo;
#pragma unroll
      for (int j2 = 0; j2 < 8; ++j2)
        wo.h[j2] = f2b(b2f(pk.h[j2]) * kdt[cq + j2]);
      *(uint4*)&ktd[d * LGC + cq] = wo.v4;
    }
    // --- stage vts [e][c] ---
#pragma unroll
    for (int p = 0; p < 4; ++p) {
      int c = (tid >> 5) + p * 16, e = tid & 31;
      vts[e * LGC + c] = v[(size_t)(row0 + c) * 4096 + hh * 512 + e0 + e];
    }
    __syncthreads();

    // --- attn = q~ k^T (wave: rows wr, col blocks eb*2+{0,1}) ---
    f32x4 att[2];
    att[0] = (f32x4){0.f, 0.f, 0.f, 0.f};
    att[1] = (f32x4){0.f, 0.f, 0.f, 0.f};
#pragma unroll
    for (int kk = 0; kk < 8; ++kk) {
#pragma unroll
      for (int jf = 0; jf < 2; ++jf) {
        u32x4 bb = *(const u32x4*)&ks[(eb * 32 + jf * 16 + lr) * LGK + kk * 32 + hi * 8];
        mfma_bf16(att[jf], qf[kk], bb);
      }
    }
    // mask -> ab
#pragma unroll
    for (int jf = 0; jf < 2; ++jf)
#pragma unroll
      for (int j = 0; j < 4; ++j) {
        int i = wr * 16 + hi * 4 + j;
        int jc = eb * 32 + jf * 16 + lr;
        float mv = (i >= jc) ? exp2f((float)(i - jc) * lg) : 0.0f;
        ab[i * LGC + jc] = f2b(att[jf][j] * mv);
      }
    // --- o_cross = q~ @ S (frag: rows wr, e block eb) ---
    f32x4 occ = (f32x4){0.f, 0.f, 0.f, 0.f};
#pragma unroll
    for (int kk = 0; kk < 8; ++kk) {
      u32x4 bb = *(const u32x4*)&stb[(eb * 16 + lr) * LGK + kk * 32 + hi * 8];
      mfma_bf16(occ, qf[kk], bb);
    }
    __syncthreads();   // ab complete; stb reads done

    // row scale gamma^(i+1)
#pragma unroll
    for (int j = 0; j < 4; ++j) {
      int i = wr * 16 + hi * 4 + j;
      occ[j] *= exp2f((float)(i + 1) * lg);
    }
    // --- o_intra: attn @ v ---
#pragma unroll
    for (int kk = 0; kk < 2; ++kk) {
      u32x4 aa = *(const u32x4*)&ab[(wr * 16 + lr) * LGC + kk * 32 + hi * 8];
      u32x4 bb = *(const u32x4*)&vts[(eb * 16 + lr) * LGC + kk * 32 + hi * 8];
      mfma_bf16(occ, aa, bb);
    }
    // --- store o ---
#pragma unroll
    for (int j = 0; j < 4; ++j) {
      int i = wr * 16 + hi * 4 + j;
      o[(size_t)(row0 + i) * 4096 + hh * 512 + e0 + eb * 16 + lr] = f2b(occ[j]);
    }
    // --- S^T = cdk*S^T + v^T @ k~ ---
#pragma unroll
    for (int t = 0; t < 4; ++t) {
      st[t][0] *= cdk; st[t][1] *= cdk; st[t][2] *= cdk; st[t][3] *= cdk;
    }
#pragma unroll
    for (int kk = 0; kk < 2; ++kk) {
      u32x4 aa = *(const u32x4*)&vts[(eb * 16 + lr) * LGC + kk * 32 + hi * 8];
#pragma unroll
      for (int t = 0; t < 4; ++t) {
        u32x4 bb = *(const u32x4*)&ktd[((wr * 4 + t) * 16 + lr) * LGC + kk * 32 + hi * 8];
        mfma_bf16(st[t], aa, bb);
      }
    }
    __syncthreads();   // staging buffers safe to overwrite next iter
  }
}

// =======================================================================
// Gated head-RMSNorm IN PLACE on o (bf16): o = rmsnorm512(o)*gnw*silu(g)
// grid = 4096*8, block = 64
// =======================================================================
__global__ __launch_bounds__(64)
void gating_kernel(u16* __restrict__ o, const u16* __restrict__ g,
                   const float* __restrict__ gnw) {
  const int blk = blockIdx.x;              // r*8 + h
  const size_t base = (size_t)blk * 512;
  const int l = threadIdx.x;
  union { uint4 v4; u16 h[8]; } ov, gv;
  ov.v4 = *(const uint4*)&o[base + l * 8];
  float x[8];
  float ss = 0.f;
#pragma unroll
  for (int j = 0; j < 8; ++j) { x[j] = b2f(ov.h[j]); ss += x[j] * x[j]; }
#pragma unroll
  for (int m = 32; m; m >>= 1) ss += __shfl_xor(ss, m);
  const float sc = rsqrtf(ss * (1.0f / 512.0f) + 1e-6f);
  gv.v4 = *(const uint4*)&g[base + l * 8];
  union { u16 h[8]; uint4 v4; } ou;
#pragma unroll
  for (int j = 0; j < 8; ++j) {
    float gvf = b2f(gv.h[j]);
    float sig = 1.0f / (1.0f + expf(-gvf));
    ou.h[j] = f2b(x[j] * sc * gnw[l * 8 + j] * gvf * sig);
  }
  *(uint4*)&o[base + l * 8] = ou.v4;
}

// =======================================================================
extern "C" void kernel_launch(void* const* d_in, const int* in_sizes, int n_in,
                              void* d_out, int out_size, void* d_ws, size_t ws_size,
                              hipStream_t stream) {
  (void)in_sizes; (void)n_in; (void)out_size; (void)ws_size;
  const float* hidden      = (const float*)d_in[0];
  const float* attn_norm_w = (const float*)d_in[1];
  const float* q_w         = (const float*)d_in[2];
  const float* k_w         = (const float*)d_in[3];
  const float* v_w         = (const float*)d_in[4];
  const float* g_w         = (const float*)d_in[5];
  const float* o_w         = (const float*)d_in[6];
  const float* gnorm_w     = (const float*)d_in[7];
  const float* mlp_norm_w  = (const float*)d_in[8];
  const float* gate_w      = (const float*)d_in[9];
  const float* down_w      = (const float*)d_in[10];
  float* outp = (float*)d_out;

  char* ws = (char*)d_ws;
  size_t off = 0;
  auto alloc = [&](size_t bytes) -> char* {
    char* p = ws + off;
    off += (bytes + 255) & ~(size_t)255;
    return p;
  };
  u16*   W    = (u16*)alloc(23068672ULL);       // weight scratch; kt aliases it
  float* ctab = (float*)alloc(1048576ULL);
  float* stab = (float*)alloc(1048576ULL);
  u16*   hb   = (u16*)alloc(16777216ULL);       // also h2b
  u16*   qb   = (u16*)alloc(16777216ULL);
  u16*   kb   = (u16*)alloc(16777216ULL);
  u16*   vb   = (u16*)alloc(33554432ULL);
  u16*   gb   = (u16*)alloc(33554432ULL);
  u16*   ob   = (u16*)alloc(33554432ULL);
  u16*   resb = (u16*)alloc(16777216ULL);
  u16*   ybU  = vb;   // [4096][5632] bf16 over vb+gb (dead post-gating)
  u16*   kt   = W;    // [16][256][2048] bf16 = 16.8MB, alive rope->retention

  rope_table_kernel<<<1024, 256, 0, stream>>>(ctab, stab);
  rmsnorm_cast_kernel<<<4096, 256, 0, stream>>>(hidden, attn_norm_w, hb);

  // Q projection
  transpose_cast_kernel<<<1024, 256, 0, stream>>>(q_w, W, 2048, 2048, 2048);
  gemm_bt<1><<<512, 256, 0, stream>>>(hb, W, (void*)qb, nullptr, nullptr, 2048, 2048);
  // K projection
  transpose_cast_kernel<<<1024, 256, 0, stream>>>(k_w, W, 2048, 2048, 2048);
  gemm_bt<1><<<512, 256, 0, stream>>>(hb, W, (void*)kb, nullptr, nullptr, 2048, 2048);
  // V projection
  transpose_cast_kernel<<<2048, 256, 0, stream>>>(v_w, W, 2048, 4096, 4096);
  gemm_bt<1><<<1024, 256, 0, stream>>>(hb, W, (void*)vb, nullptr, nullptr, 4096, 2048);
  // G projection
  transpose_cast_kernel<<<2048, 256, 0, stream>>>(g_w, W, 2048, 4096, 4096);
  gemm_bt<1><<<1024, 256, 0, stream>>>(hb, W, (void*)gb, nullptr, nullptr, 4096, 2048);

  // RoPE (+ q scale 1/16), then k -> kt (W is dead until o-proj transpose)
  rope_apply_kernel<<<4096, 256, 0, stream>>>(qb, ctab, stab, 0.0625f);
  rope_apply_kernel<<<4096, 256, 0, stream>>>(kb, ctab, stab, 1.0f);
  transpose_k_kernel<<<2048, 256, 0, stream>>>(kb, kt);

  // Retention scan -> ob (bf16)
  retention_kernel<<<256, 512, 0, stream>>>(qb, kb, kt, vb, ob);

  // Gated head RMSNorm in place on ob
  gating_kernel<<<32768, 64, 0, stream>>>(ob, gb, gnorm_w);

  // O projection + residual(hidden) -> resb (bf16)
  transpose_cast_kernel<<<2048, 256, 0, stream>>>(o_w, W, 4096, 2048, 2048);
  gemm_bt<4><<<512, 256, 0, stream>>>(ob, W, (void*)resb, hidden, nullptr, 2048, 4096);

  // MLP RMSNorm (h2b reuses hb)
  rmsnorm_bf16_kernel<<<4096, 256, 0, stream>>>(resb, mlp_norm_w, hb);

  // Up-half GEMM -> ybU
  transpose_cast_kernel<<<2816, 256, 0, stream>>>(gate_w + 5632, W, 2048, 5632, 11264);
  gemm_bt<1><<<1408, 256, 0, stream>>>(hb, W, (void*)ybU, nullptr, nullptr, 5632, 2048);
  // Gate-half GEMM with fused SwiGLU, in place over ybU
  transpose_cast_kernel<<<2816, 256, 0, stream>>>(gate_w, W, 2048, 5632, 11264);
  gemm_bt<3><<<1408, 256, 0, stream>>>(hb, W, (void*)ybU, nullptr, ybU, 5632, 2048);

  // Down projection + residual(resb) -> d_out (f32)
  transpose_cast_kernel<<<2816, 256, 0, stream>>>(down_w, W, 5632, 2048, 2048);
  gemm_bt<2><<<512, 256, 0, stream>>>(ybU, W, (void*)outp, nullptr, resb, 2048, 5632);
}

// Round 4
// 960.972 us; speedup vs baseline: 1.1424x; 1.0824x over previous
//
#include <hip/hip_runtime.h>
#include <cstdint>
#include <cstddef>

typedef unsigned short u16;
typedef __attribute__((ext_vector_type(4))) float f32x4;
typedef __attribute__((ext_vector_type(4))) unsigned int u32x4;

// ---------- bf16 helpers (bit-level) ----------
__device__ __forceinline__ float b2f(u16 u) {
  union { unsigned int i; float f; } x; x.i = ((unsigned int)u) << 16; return x.f;
}
__device__ __forceinline__ u16 f2b(float f) {
  union { float f; unsigned int i; } x; x.f = f;
  unsigned int i = x.i;
  i += 0x7fffu + ((i >> 16) & 1u);   // RNE
  return (u16)(i >> 16);
}

// ---------- MFMA via inline asm ----------
__device__ __forceinline__ void mfma_bf16(f32x4& c, u32x4 a, u32x4 b) {
  asm("v_mfma_f32_16x16x32_bf16 %0, %1, %2, %0" : "+v"(c) : "v"(a), "v"(b));
}

// ---------- async global->LDS, 16B per lane ----------
__device__ __forceinline__ void async_ld16(const u16* g, u16* l) {
  typedef __attribute__((address_space(1))) const unsigned int GU;
  typedef __attribute__((address_space(3))) unsigned int LU;
  __builtin_amdgcn_global_load_lds((GU*)g, (LU*)l, 16, 0, 0);
}

// =======================================================================
// Weight transpose + cast: in[K][ldin] f32 (use N cols) -> out[N][K] bf16
// =======================================================================
__global__ __launch_bounds__(256)
void transpose_cast_kernel(const float* __restrict__ in, u16* __restrict__ out,
                           int K, int N, int ldin) {
  __shared__ float tile[64][65];
  const int nb = N >> 6;
  const int bk = blockIdx.x / nb, bn = blockIdx.x % nb;
  const int k0 = bk * 64, n0 = bn * 64;
  const int tid = threadIdx.x;
#pragma unroll
  for (int p = 0; p < 16; ++p) {
    int idx = p * 256 + tid;
    int r = idx >> 6, c = idx & 63;
    tile[r][c] = in[(size_t)(k0 + r) * ldin + n0 + c];
  }
  __syncthreads();
#pragma unroll
  for (int p = 0; p < 16; ++p) {
    int idx = p * 256 + tid;
    int r = idx >> 6, c = idx & 63;
    out[(size_t)(n0 + r) * K + k0 + c] = f2b(tile[c][r]);
  }
}

// =======================================================================
// k transpose: kb [b*2048 + t][h*256 + d] bf16 -> kt [(b*8+h)*256 + d][t]
// grid = 2048, block 256
// =======================================================================
__global__ __launch_bounds__(256)
void transpose_k_kernel(const u16* __restrict__ kb, u16* __restrict__ kt) {
  __shared__ u16 tile[64][72];
  const int bid = blockIdx.x;
  const int dd = bid & 3, tt = (bid >> 2) & 31;
  const int h = (bid >> 7) & 7, b = bid >> 10;
  const int t0 = tt * 64, d0 = dd * 64;
  const int tid = threadIdx.x;
#pragma unroll
  for (int p = 0; p < 2; ++p) {
    int idx = p * 256 + tid;
    int r = idx >> 3, cq = (idx & 7) * 8;
    *(uint4*)&tile[r][cq] =
        *(const uint4*)&kb[(size_t)(b * 2048 + t0 + r) * 2048 + h * 256 + d0 + cq];
  }
  __syncthreads();
#pragma unroll
  for (int p = 0; p < 2; ++p) {
    int idx = p * 256 + tid;
    int r = idx >> 3, cq = (idx & 7) * 8;
    union { u16 h8[8]; uint4 v4; } o;
#pragma unroll
    for (int j = 0; j < 8; ++j) o.h8[j] = tile[cq + j][r];
    *(uint4*)&kt[((size_t)(b * 8 + h) * 256 + d0 + r) * 2048 + t0 + cq] = o.v4;
  }
}

// =======================================================================
// RMSNorm over 2048 f32 -> bf16
// =======================================================================
__global__ __launch_bounds__(256)
void rmsnorm_cast_kernel(const float* __restrict__ x, const float* __restrict__ w,
                         u16* __restrict__ out) {
  const int row = blockIdx.x, tid = threadIdx.x;
  const float* xr = x + (size_t)row * 2048;
  float4 a = ((const float4*)xr)[tid * 2];
  float4 b = ((const float4*)xr)[tid * 2 + 1];
  float ss = a.x*a.x + a.y*a.y + a.z*a.z + a.w*a.w
           + b.x*b.x + b.y*b.y + b.z*b.z + b.w*b.w;
#pragma unroll
  for (int m = 32; m; m >>= 1) ss += __shfl_xor(ss, m);
  __shared__ float ps[4];
  if ((tid & 63) == 0) ps[tid >> 6] = ss;
  __syncthreads();
  const float sc = rsqrtf((ps[0] + ps[1] + ps[2] + ps[3]) * (1.0f / 2048.0f) + 1e-6f);
  const int base = tid * 8;
  const float vals[8] = {a.x, a.y, a.z, a.w, b.x, b.y, b.z, b.w};
  union { u16 h[8]; uint4 v4[2]; } o;
#pragma unroll
  for (int j = 0; j < 8; ++j) o.h[j] = f2b(vals[j] * sc * w[base + j]);
  *(uint4*)&out[(size_t)row * 2048 + base] = o.v4[0];
  *(uint4*)&out[(size_t)row * 2048 + base + 8] = o.v4[1];
}

// =======================================================================
// RMSNorm over 2048 bf16 -> bf16
// =======================================================================
__global__ __launch_bounds__(256)
void rmsnorm_bf16_kernel(const u16* __restrict__ x, const float* __restrict__ w,
                         u16* __restrict__ out) {
  const int row = blockIdx.x, tid = threadIdx.x;
  union { uint4 v4; u16 h[8]; } p;
  p.v4 = *(const uint4*)&x[(size_t)row * 2048 + tid * 8];
  float v[8];
  float ss = 0.f;
#pragma unroll
  for (int j = 0; j < 8; ++j) { v[j] = b2f(p.h[j]); ss += v[j] * v[j]; }
#pragma unroll
  for (int m = 32; m; m >>= 1) ss += __shfl_xor(ss, m);
  __shared__ float ps[4];
  if ((tid & 63) == 0) ps[tid >> 6] = ss;
  __syncthreads();
  const float sc = rsqrtf((ps[0] + ps[1] + ps[2] + ps[3]) * (1.0f / 2048.0f) + 1e-6f);
  union { u16 h[8]; uint4 v4; } o;
#pragma unroll
  for (int j = 0; j < 8; ++j) o.h[j] = f2b(v[j] * sc * w[tid * 8 + j]);
  *(uint4*)&out[(size_t)row * 2048 + tid * 8] = o.v4;
}

// =======================================================================
// RoPE tables
// =======================================================================
__global__ __launch_bounds__(256)
void rope_table_kernel(float* __restrict__ ct, float* __restrict__ st) {
  const int idx = blockIdx.x * 256 + threadIdx.x;
  const int t = idx >> 7, i = idx & 127;
  const float e = -(float)i * (0.0078125f * log2f(10000.0f));
  const float ang = (float)t * exp2f(e);
  ct[idx] = cosf(ang);
  st[idx] = sinf(ang);
}

// =======================================================================
// RoPE apply in-place
// =======================================================================
__global__ __launch_bounds__(256)
void rope_apply_kernel(u16* __restrict__ x, const float* __restrict__ ct,
                       const float* __restrict__ st, float scale) {
  const int gid = blockIdx.x * 256 + threadIdx.x;
  const int r = gid >> 8;
  const int rem = gid & 255;
  const int h = rem >> 5;
  const int i4 = (rem & 31) * 4;
  const int t = r & 2047;
  const size_t o1 = (size_t)r * 2048 + h * 256 + i4;
  union { ushort4 v; u16 h4[4]; } p1, p2, q1, q2;
  p1.v = *(ushort4*)&x[o1];
  p2.v = *(ushort4*)&x[o1 + 128];
  const float4 c = *(const float4*)&ct[t * 128 + i4];
  const float4 s = *(const float4*)&st[t * 128 + i4];
  const float cc[4] = {c.x, c.y, c.z, c.w};
  const float sn[4] = {s.x, s.y, s.z, s.w};
#pragma unroll
  for (int j = 0; j < 4; ++j) {
    float x1 = b2f(p1.h4[j]), x2 = b2f(p2.h4[j]);
    q1.h4[j] = f2b((x1 * cc[j] - x2 * sn[j]) * scale);
    q2.h4[j] = f2b((x2 * cc[j] + x1 * sn[j]) * scale);
  }
  *(ushort4*)&x[o1] = q1.v;
  *(ushort4*)&x[o1 + 128] = q2.v;
}

// =======================================================================
// GEMM v2: C[M,N] = A[M,K](bf16) x Bt[N,K](bf16), fp32 accum.
// BM x 256 tile, BK=32, 8 waves (512 thr), 4-slot LDS pipeline with
// prefetch distance 3 and counted vmcnt (never 0). XOR chunk-swizzle on
// LDS (inverse-swizzled global source + swizzled ds_read). XCD-chunked
// blockIdx (grid must be %8==0). M%BM==0, N%256==0, K%32==0, K/32>=4.
// EPI: 1 bf16; 2 f32 acc+b2f(hsrc); 3 bf16 silu(acc)*b2f(hsrc); 4 bf16 acc+fsrc
// =======================================================================
template <int BM, int EPI>
__global__ __launch_bounds__(512, 2)
void gemm2(const u16* __restrict__ A, const u16* __restrict__ Bt,
           void* Cout, const float* fsrc, const u16* hsrc, int N, int K) {
  constexpr int MF = BM / 32;        // m-frags per wave
  constexpr int WROWS = BM / 2;      // rows per wave half
  constexpr int LA = BM / 128;       // A stage loads per thread
  constexpr int SLOTA = BM * 32;     // u16 per A slot
  constexpr int SLOTB = 256 * 32;
  constexpr int SLOT = SLOTA + SLOTB;
  constexpr int VM2 = 2 * (LA + 2);  // vmcnt allowance = 2 tiles in flight
  __shared__ __align__(16) u16 lds[4 * SLOT];

  const int tid = threadIdx.x;
  const int l = tid & 63, w = tid >> 6;
  const int lr = l & 15, hi = l >> 4;
  const int wm = w >> 2, wn = w & 3;
  const int nbn = N >> 8;
  int bid;
  { int cpx = (int)gridDim.x >> 3; int ob = blockIdx.x;
    bid = (ob & 7) * cpx + (ob >> 3); }
  const int bm = bid / nbn, bn = bid % nbn;
  const int nt = K >> 5;

  // staging precompute (per-thread global src, wave-uniform LDS dst)
  size_t asrc[LA]; int adst[LA];
#pragma unroll
  for (int t = 0; t < LA; ++t) {
    int gi = t * 512 + tid;
    int row = gi >> 2;
    int ch = (gi & 3) ^ (row & 3);
    asrc[t] = (size_t)(bm * BM + row) * K + ch * 8;
    adst[t] = (t * 512 + w * 64) * 8;
  }
  size_t bsrc[2]; int bdst[2];
#pragma unroll
  for (int t = 0; t < 2; ++t) {
    int gi = t * 512 + tid;
    int row = gi >> 2;
    int ch = (gi & 3) ^ (row & 3);
    bsrc[t] = (size_t)(bn * 256 + row) * K + ch * 8;
    bdst[t] = SLOTA + (t * 512 + w * 64) * 8;
  }
  // frag read offsets (u16 elements within a slot)
  const int xch = (hi ^ (lr & 3)) << 3;
  int aoff[MF], boff[4];
#pragma unroll
  for (int m = 0; m < MF; ++m)
    aoff[m] = (wm * WROWS + m * 16 + lr) * 32 + xch;
#pragma unroll
  for (int n = 0; n < 4; ++n)
    boff[n] = SLOTA + (wn * 64 + n * 16 + lr) * 32 + xch;

  f32x4 acc[MF][4];
#pragma unroll
  for (int m = 0; m < MF; ++m)
#pragma unroll
    for (int n = 0; n < 4; ++n) acc[m][n] = (f32x4){0.f, 0.f, 0.f, 0.f};

  auto stage = [&](int kt, int s) {
    const int sb = s * SLOT;
#pragma unroll
    for (int t = 0; t < LA; ++t)
      async_ld16(A + (asrc[t] + kt * 32), &lds[sb + adst[t]]);
#pragma unroll
    for (int t = 0; t < 2; ++t)
      async_ld16(Bt + (bsrc[t] + kt * 32), &lds[sb + bdst[t]]);
  };

  // prologue: tiles 0,1,2 -> slots 0,1,2 (FIFO order pinned)
  stage(0, 0); __builtin_amdgcn_sched_barrier(0);
  stage(1, 1); __builtin_amdgcn_sched_barrier(0);
  stage(2, 2); __builtin_amdgcn_sched_barrier(0);
  asm volatile("s_waitcnt vmcnt(%0)" :: "n"(VM2) : "memory");
  __builtin_amdgcn_sched_barrier(0);
  __builtin_amdgcn_s_barrier();
  __builtin_amdgcn_sched_barrier(0);

  for (int i = 0; i < nt; ++i) {
    int pf = i + 3; if (pf >= nt) pf -= nt;   // tail: re-stage into dead slot
    stage(pf, (i + 3) & 3);
    __builtin_amdgcn_sched_barrier(0);
    const int sb = (i & 3) * SLOT;
    u32x4 af[MF], bf[4];
#pragma unroll
    for (int m = 0; m < MF; ++m) af[m] = *(const u32x4*)&lds[sb + aoff[m]];
#pragma unroll
    for (int n = 0; n < 4; ++n) bf[n] = *(const u32x4*)&lds[sb + boff[n]];
    __builtin_amdgcn_s_setprio(1);
#pragma unroll
    for (int m = 0; m < MF; ++m)
#pragma unroll
      for (int n = 0; n < 4; ++n) mfma_bf16(acc[m][n], af[m], bf[n]);
    __builtin_amdgcn_s_setprio(0);
    __builtin_amdgcn_sched_barrier(0);
    asm volatile("s_waitcnt vmcnt(%0)" :: "n"(VM2) : "memory");
    __builtin_amdgcn_sched_barrier(0);
    __builtin_amdgcn_s_barrier();
    __builtin_amdgcn_sched_barrier(0);
  }

  const size_t crow0 = (size_t)(bm * BM + wm * WROWS);
  const int ccol0 = bn * 256 + wn * 64;
#pragma unroll
  for (int m = 0; m < MF; ++m)
#pragma unroll
    for (int n = 0; n < 4; ++n)
#pragma unroll
      for (int j = 0; j < 4; ++j) {
        size_t r = crow0 + m * 16 + hi * 4 + j;
        size_t c = (size_t)(ccol0 + n * 16 + lr);
        size_t idx = r * N + c;
        float a = acc[m][n][j];
        if (EPI == 1) {
          ((u16*)Cout)[idx] = f2b(a);
        } else if (EPI == 2) {
          ((float*)Cout)[idx] = a + b2f(hsrc[idx]);
        } else if (EPI == 3) {
          float u = b2f(hsrc[idx]);
          ((u16*)Cout)[idx] = f2b(a / (1.0f + expf(-a)) * u);
        } else {
          ((u16*)Cout)[idx] = f2b(a + fsrc[idx]);
        }
      }
}

// =======================================================================
// Chunkwise retention scan (v2 + XCD-locality bid decode).
// grid = 256, block = 512.  bid = sl*16 + (b*8+hh) so the 16 e-slices of
// one (b,h) land on one XCD's L2 (q/k/kt reuse).
// =======================================================================
#define LGK 264
#define LGC 72
__global__ __launch_bounds__(512)
void retention_kernel(const u16* __restrict__ q, const u16* __restrict__ k,
                      const u16* __restrict__ kt, const u16* __restrict__ v,
                      u16* __restrict__ o) {
  __shared__ __align__(16) u16 ks[64 * LGK];
  __shared__ __align__(16) u16 stb[32 * LGK];
  __shared__ __align__(16) u16 ktd[256 * LGC];
  __shared__ __align__(16) u16 vts[32 * LGC];
  __shared__ __align__(16) u16 ab[64 * LGC];
  __shared__ float kdt[64];

  const int tid = threadIdx.x;
  const int l = tid & 63, w = tid >> 6;
  const int lr = l & 15, hi = l >> 4;
  const int wr = w >> 1;
  const int eb = w & 1;
  const int bid = blockIdx.x;
  const int g = bid & 15;
  const int sl = bid >> 4;
  const int hh = g & 7;
  const int b = g >> 3;
  const float gamma = 1.0f - exp2f(-5.0f - (float)hh);
  const float lg = log2f(gamma);
  const float cdk = exp2f(64.0f * lg);
  const int e0 = sl * 32;

  if (tid < 64) kdt[tid] = exp2f((float)(63 - tid) * lg);
  __syncthreads();

  f32x4 st[4];
#pragma unroll
  for (int t = 0; t < 4; ++t) st[t] = (f32x4){0.f, 0.f, 0.f, 0.f};

  for (int n = 0; n < 32; ++n) {
    const int row0 = b * 2048 + n * 64;
    const int t0 = n * 64;
#pragma unroll
    for (int t = 0; t < 4; ++t)
#pragma unroll
      for (int j = 0; j < 4; ++j)
        stb[(eb * 16 + hi * 4 + j) * LGK + (wr * 4 + t) * 16 + lr] = f2b(st[t][j]);
    u32x4 qf[8];
#pragma unroll
    for (int kk = 0; kk < 8; ++kk)
      qf[kk] = *(const u32x4*)&q[(size_t)(row0 + wr * 16 + lr) * 2048 +
                                 hh * 256 + kk * 32 + hi * 8];
#pragma unroll
    for (int p = 0; p < 4; ++p) {
      int idx = p * 512 + tid;
      int c = idx >> 5, s = (idx & 31) * 8;
      *(uint4*)&ks[c * LGK + s] =
          *(const uint4*)&k[(size_t)(row0 + c) * 2048 + hh * 256 + s];
    }
#pragma unroll
    for (int p = 0; p < 4; ++p) {
      int idx = p * 512 + tid;
      int d = idx >> 3, cq = (idx & 7) * 8;
      union { uint4 v4; u16 h[8]; } pk;
      pk.v4 = *(const uint4*)&kt[((size_t)(b * 8 + hh) * 256 + d) * 2048 + t0 + cq];
      union { u16 h[8]; uint4 v4; } wo;
#pragma unroll
      for (int j2 = 0; j2 < 8; ++j2)
        wo.h[j2] = f2b(b2f(pk.h[j2]) * kdt[cq + j2]);
      *(uint4*)&ktd[d * LGC + cq] = wo.v4;
    }
#pragma unroll
    for (int p = 0; p < 4; ++p) {
      int c = (tid >> 5) + p * 16, e = tid & 31;
      vts[e * LGC + c] = v[(size_t)(row0 + c) * 4096 + hh * 512 + e0 + e];
    }
    __syncthreads();

    f32x4 att[2];
    att[0] = (f32x4){0.f, 0.f, 0.f, 0.f};
    att[1] = (f32x4){0.f, 0.f, 0.f, 0.f};
#pragma unroll
    for (int kk = 0; kk < 8; ++kk) {
#pragma unroll
      for (int jf = 0; jf < 2; ++jf) {
        u32x4 bb = *(const u32x4*)&ks[(eb * 32 + jf * 16 + lr) * LGK + kk * 32 + hi * 8];
        mfma_bf16(att[jf], qf[kk], bb);
      }
    }
#pragma unroll
    for (int jf = 0; jf < 2; ++jf)
#pragma unroll
      for (int j = 0; j < 4; ++j) {
        int i = wr * 16 + hi * 4 + j;
        int jc = eb * 32 + jf * 16 + lr;
        float mv = (i >= jc) ? exp2f((float)(i - jc) * lg) : 0.0f;
        ab[i * LGC + jc] = f2b(att[jf][j] * mv);
      }
    f32x4 occ = (f32x4){0.f, 0.f, 0.f, 0.f};
#pragma unroll
    for (int kk = 0; kk < 8; ++kk) {
      u32x4 bb = *(const u32x4*)&stb[(eb * 16 + lr) * LGK + kk * 32 + hi * 8];
      mfma_bf16(occ, qf[kk], bb);
    }
    __syncthreads();

#pragma unroll
    for (int j = 0; j < 4; ++j) {
      int i = wr * 16 + hi * 4 + j;
      occ[j] *= exp2f((float)(i + 1) * lg);
    }
#pragma unroll
    for (int kk = 0; kk < 2; ++kk) {
      u32x4 aa = *(const u32x4*)&ab[(wr * 16 + lr) * LGC + kk * 32 + hi * 8];
      u32x4 bb = *(const u32x4*)&vts[(eb * 16 + lr) * LGC + kk * 32 + hi * 8];
      mfma_bf16(occ, aa, bb);
    }
#pragma unroll
    for (int j = 0; j < 4; ++j) {
      int i = wr * 16 + hi * 4 + j;
      o[(size_t)(row0 + i) * 4096 + hh * 512 + e0 + eb * 16 + lr] = f2b(occ[j]);
    }
#pragma unroll
    for (int t = 0; t < 4; ++t) {
      st[t][0] *= cdk; st[t][1] *= cdk; st[t][2] *= cdk; st[t][3] *= cdk;
    }
#pragma unroll
    for (int kk = 0; kk < 2; ++kk) {
      u32x4 aa = *(const u32x4*)&vts[(eb * 16 + lr) * LGC + kk * 32 + hi * 8];
#pragma unroll
      for (int t = 0; t < 4; ++t) {
        u32x4 bb = *(const u32x4*)&ktd[((wr * 4 + t) * 16 + lr) * LGC + kk * 32 + hi * 8];
        mfma_bf16(st[t], aa, bb);
      }
    }
    __syncthreads();
  }
}

// =======================================================================
// Gated head-RMSNorm IN PLACE on o (bf16)
// =======================================================================
__global__ __launch_bounds__(64)
void gating_kernel(u16* __restrict__ o, const u16* __restrict__ g,
                   const float* __restrict__ gnw) {
  const int blk = blockIdx.x;
  const size_t base = (size_t)blk * 512;
  const int l = threadIdx.x;
  union { uint4 v4; u16 h[8]; } ov, gv;
  ov.v4 = *(const uint4*)&o[base + l * 8];
  float x[8];
  float ss = 0.f;
#pragma unroll
  for (int j = 0; j < 8; ++j) { x[j] = b2f(ov.h[j]); ss += x[j] * x[j]; }
#pragma unroll
  for (int m = 32; m; m >>= 1) ss += __shfl_xor(ss, m);
  const float sc = rsqrtf(ss * (1.0f / 512.0f) + 1e-6f);
  gv.v4 = *(const uint4*)&g[base + l * 8];
  union { u16 h[8]; uint4 v4; } ou;
#pragma unroll
  for (int j = 0; j < 8; ++j) {
    float gvf = b2f(gv.h[j]);
    float sig = 1.0f / (1.0f + expf(-gvf));
    ou.h[j] = f2b(x[j] * sc * gnw[l * 8 + j] * gvf * sig);
  }
  *(uint4*)&o[base + l * 8] = ou.v4;
}

// =======================================================================
// SwiGLU done in gemm2<_,3>; workspace plan identical to round 2 (193 MB)
// =======================================================================
extern "C" void kernel_launch(void* const* d_in, const int* in_sizes, int n_in,
                              void* d_out, int out_size, void* d_ws, size_t ws_size,
                              hipStream_t stream) {
  (void)in_sizes; (void)n_in; (void)out_size; (void)ws_size;
  const float* hidden      = (const float*)d_in[0];
  const float* attn_norm_w = (const float*)d_in[1];
  const float* q_w         = (const float*)d_in[2];
  const float* k_w         = (const float*)d_in[3];
  const float* v_w         = (const float*)d_in[4];
  const float* g_w         = (const float*)d_in[5];
  const float* o_w         = (const float*)d_in[6];
  const float* gnorm_w     = (const float*)d_in[7];
  const float* mlp_norm_w  = (const float*)d_in[8];
  const float* gate_w      = (const float*)d_in[9];
  const float* down_w      = (const float*)d_in[10];
  float* outp = (float*)d_out;

  char* ws = (char*)d_ws;
  size_t off = 0;
  auto alloc = [&](size_t bytes) -> char* {
    char* p = ws + off;
    off += (bytes + 255) & ~(size_t)255;
    return p;
  };
  u16*   W    = (u16*)alloc(23068672ULL);
  float* ctab = (float*)alloc(1048576ULL);
  float* stab = (float*)alloc(1048576ULL);
  u16*   hb   = (u16*)alloc(16777216ULL);
  u16*   qb   = (u16*)alloc(16777216ULL);
  u16*   kb   = (u16*)alloc(16777216ULL);
  u16*   vb   = (u16*)alloc(33554432ULL);
  u16*   gb   = (u16*)alloc(33554432ULL);
  u16*   ob   = (u16*)alloc(33554432ULL);
  u16*   resb = (u16*)alloc(16777216ULL);
  u16*   ybU  = vb;   // reused after vb/gb dead
  u16*   kt   = W;    // reused while W idle (rope -> retention)

  rope_table_kernel<<<1024, 256, 0, stream>>>(ctab, stab);
  rmsnorm_cast_kernel<<<4096, 256, 0, stream>>>(hidden, attn_norm_w, hb);

  // Q projection (M4096 N2048 K2048)
  transpose_cast_kernel<<<1024, 256, 0, stream>>>(q_w, W, 2048, 2048, 2048);
  gemm2<128, 1><<<256, 512, 0, stream>>>(hb, W, (void*)qb, nullptr, nullptr, 2048, 2048);
  // K projection
  transpose_cast_kernel<<<1024, 256, 0, stream>>>(k_w, W, 2048, 2048, 2048);
  gemm2<128, 1><<<256, 512, 0, stream>>>(hb, W, (void*)kb, nullptr, nullptr, 2048, 2048);
  // V projection (N4096)
  transpose_cast_kernel<<<2048, 256, 0, stream>>>(v_w, W, 2048, 4096, 4096);
  gemm2<256, 1><<<256, 512, 0, stream>>>(hb, W, (void*)vb, nullptr, nullptr, 4096, 2048);
  // G projection
  transpose_cast_kernel<<<2048, 256, 0, stream>>>(g_w, W, 2048, 4096, 4096);
  gemm2<256, 1><<<256, 512, 0, stream>>>(hb, W, (void*)gb, nullptr, nullptr, 4096, 2048);

  // RoPE (+ q scale 1/16), then k -> kt
  rope_apply_kernel<<<4096, 256, 0, stream>>>(qb, ctab, stab, 0.0625f);
  rope_apply_kernel<<<4096, 256, 0, stream>>>(kb, ctab, stab, 1.0f);
  transpose_k_kernel<<<2048, 256, 0, stream>>>(kb, kt);

  // Retention scan -> ob (bf16)
  retention_kernel<<<256, 512, 0, stream>>>(qb, kb, kt, vb, ob);

  // Gated head RMSNorm in place on ob
  gating_kernel<<<32768, 64, 0, stream>>>(ob, gb, gnorm_w);

  // O projection + residual(hidden) -> resb (N2048 K4096)
  transpose_cast_kernel<<<2048, 256, 0, stream>>>(o_w, W, 4096, 2048, 2048);
  gemm2<128, 4><<<256, 512, 0, stream>>>(ob, W, (void*)resb, hidden, nullptr, 2048, 4096);

  // MLP RMSNorm
  rmsnorm_bf16_kernel<<<4096, 256, 0, stream>>>(resb, mlp_norm_w, hb);

  // Up-half GEMM -> ybU (N5632 K2048)
  transpose_cast_kernel<<<2816, 256, 0, stream>>>(gate_w + 5632, W, 2048, 5632, 11264);
  gemm2<128, 1><<<704, 512, 0, stream>>>(hb, W, (void*)ybU, nullptr, nullptr, 5632, 2048);
  // Gate-half GEMM fused SwiGLU in place over ybU
  transpose_cast_kernel<<<2816, 256, 0, stream>>>(gate_w, W, 2048, 5632, 11264);
  gemm2<128, 3><<<704, 512, 0, stream>>>(hb, W, (void*)ybU, nullptr, ybU, 5632, 2048);

  // Down projection + residual(resb) -> d_out (N2048 K5632)
  transpose_cast_kernel<<<2816, 256, 0, stream>>>(down_w, W, 5632, 2048, 2048);
  gemm2<128, 2><<<256, 512, 0, stream>>>(ybU, W, (void*)outp, nullptr, resb, 2048, 5632);
}